// Round 4
// baseline (387.614 us; speedup 1.0000x reference)
//
#include <hip/hip_runtime.h>
#include <stdint.h>

// BitNet-style fused 3-layer MLP for MI355X (gfx950) — round 6.
//
// Round-5 post-mortem: fused kernel REGRESSED ~12-14 us vs the round-4 split
// (fills were even slightly faster). Revised theory: the wave-0 l2+l3 tail
// added ~60 live VGPRs; crossing the 128-VGPR cliff halves waves/CU 16->8,
// which slows the latency-hiding of the x prefetch stream (the real payload).
// Round-6 fixes:
//   - __launch_bounds__(256, 4): force >=4 waves/EU (VGPR cap 128).
//   - leaner tail: MFMA2 per nt-block -> immediate dequant+relu into LDS
//     h2f[16][68] (4.3 KB), re-read token-major (= MFMA3 A-frag layout).
//     Kills h2v[16]/acc[16]/vector stats regs, the wbuf transpose, and the
//     t3 k-permutation (t3 is now plain row-major).
//
// ws layout (offsets mult of 256):
//   0        double sums[3]
//   1024     t1:  128 x 832 int8 ternary w1 (K 784->832 zero-pad)   106496 B
//   107520   t2:  64 x 128 int8 ternary w2                            8192 B
//   115712   t3:  16 x 64  int8 ternary w3, rows 10..15 = 0           1024 B

typedef int   ix4 __attribute__((ext_vector_type(4)));
typedef float fx4 __attribute__((ext_vector_type(4)));

#define MFMA_I8(a, b, c) __builtin_amdgcn_mfma_i32_16x16x64_i8((a), (b), (c), 0, 0, 0)

// Barrier that waits LDS ops only; global loads (prefetch) stay in flight.
__device__ __forceinline__ void sync_lds() {
  asm volatile("s_waitcnt lgkmcnt(0)" ::: "memory");
  __builtin_amdgcn_s_barrier();
}
__device__ __forceinline__ void wave_lds_fence() {
  asm volatile("s_waitcnt lgkmcnt(0)" ::: "memory");
}

// ---------------------------------------------------------------- prep 1
__global__ __launch_bounds__(256) void prep_mean(
    const float* __restrict__ w1, const float* __restrict__ w2,
    const float* __restrict__ w3, double* __restrict__ sums) {
  __shared__ double red[256];
  const int b = blockIdx.x;
  const float* w; int n, nb, bb, which;
  if (b < 240)      { w = w1; n = 128 * 784; nb = 240; bb = b;       which = 0; }
  else if (b < 248) { w = w2; n = 64 * 128;  nb = 8;   bb = b - 240; which = 1; }
  else              { w = w3; n = 10 * 64;   nb = 1;   bb = 0;       which = 2; }
  double s = 0.0;
  for (int i = bb * 256 + (int)threadIdx.x; i < n; i += nb * 256)
    s += (double)fabsf(w[i]);
  red[threadIdx.x] = s;
  __syncthreads();
  for (int off = 128; off > 0; off >>= 1) {
    if ((int)threadIdx.x < off) red[threadIdx.x] += red[threadIdx.x + off];
    __syncthreads();
  }
  if (threadIdx.x == 0) atomicAdd(&sums[which], red[0]);
}

// ---------------------------------------------------------------- prep 2
__global__ __launch_bounds__(256) void prep_quant(
    const float* __restrict__ w1, const float* __restrict__ w2,
    const float* __restrict__ w3, const double* __restrict__ sums,
    int8_t* __restrict__ t1, int8_t* __restrict__ t2,
    int8_t* __restrict__ t3) {
  const int idx = blockIdx.x * 256 + (int)threadIdx.x;
  const float s1 = 1.0f / fmaxf((float)(sums[0] * (1.0 / (128.0 * 784.0))), 1e-5f);
  const float s2 = 1.0f / fmaxf((float)(sums[1] * (1.0 / (64.0 * 128.0))), 1e-5f);
  const float s3 = 1.0f / fmaxf((float)(sums[2] * (1.0 / (10.0 * 64.0))), 1e-5f);
  if (idx < 128 * 832) {
    const int n = idx / 832, k = idx - n * 832;
    float v = 0.f;
    if (k < 784) v = fminf(fmaxf(rintf(w1[n * 784 + k] * s1), -1.f), 1.f);
    t1[idx] = (int8_t)(int)v;
  } else if (idx < 128 * 832 + 64 * 128) {
    const int i = idx - 128 * 832;
    t2[i] = (int8_t)(int)fminf(fmaxf(rintf(w2[i] * s2), -1.f), 1.f);
  } else if (idx < 128 * 832 + 64 * 128 + 16 * 64) {
    const int i = idx - (128 * 832 + 64 * 128);
    const int n = i >> 6, k = i & 63;
    float v = 0.f;
    if (n < 10) v = fminf(fmaxf(rintf(w3[n * 64 + k] * s3), -1.f), 1.f);
    t3[i] = (int8_t)(int)v;
  }
}

// ---------------------------------------------------------------- fused ffn
// Persistent; 16 tokens/tile; lane roles: wv=wave, g=l>>4, sl=l&15;
// L1 quant token = wv*4+g. i8 MFMA A: A[m=sl][k=64kk+16g+j]; D[4g+r][sl].
// After BAR2, wave 0 alone runs layers 2+3 in-wave (no extra barriers).
__global__ __launch_bounds__(256, 4)  // >=4 waves/EU => VGPR cap 128 (occupancy cliff at 128, m69)
void ffn_fused(
    const float* __restrict__ x,
    const float* __restrict__ sc1, const float* __restrict__ sc2,
    const float* __restrict__ sc3,
    const int8_t* __restrict__ t1, const int8_t* __restrict__ t2,
    const int8_t* __restrict__ t3, const double* __restrict__ sums,
    float* __restrict__ out, int numTiles) {
  __shared__ int8_t q1[16 * 848];   // 13.6 KB
  __shared__ float  h1[16 * 132];   // 8.4 KB
  __shared__ float  inv1[16];
  __shared__ float  h2f[16 * 68];   // 4.3 KB, wave-0 private l2-output buffer

  const int tid = threadIdx.x;
  const int l   = tid & 63;
  const int wv  = tid >> 6;
  const int g   = l >> 4;
  const int sl  = l & 15;
  const int token = wv * 4 + g;

  const float m1 = fmaxf((float)(sums[0] * (1.0 / (128.0 * 784.0))), 1e-5f);
  const float m2 = fmaxf((float)(sums[1] * (1.0 / (64.0 * 128.0))), 1e-5f);
  const float m3 = fmaxf((float)(sums[2] * (1.0 / (10.0 * 64.0))), 1e-5f);

  // zero q1's K-pad [784,832) once
  if (tid < 192) {
    const int t = tid / 12, c = tid - (tid / 12) * 12;
    *reinterpret_cast<unsigned*>(&q1[t * 848 + 784 + c * 4]) = 0u;
  }

  fx4 xv[13];
  int tile = blockIdx.x;
  if (tile < numTiles) {
    const float* rowp = x + (size_t)(tile * 16 + token) * 784;
#pragma unroll
    for (int c = 0; c < 12; ++c)
      xv[c] = *reinterpret_cast<const fx4*>(rowp + (sl + 16 * c) * 4);
    if (sl < 4) xv[12] = *reinterpret_cast<const fx4*>(rowp + (sl + 192) * 4);
  }

  for (; tile < numTiles; tile += (int)gridDim.x) {
    // ---- stats: sumsq(x) + max|sc1*x| ----
    float ss = 0.f, am = 0.f;
#pragma unroll
    for (int c = 0; c < 12; ++c) {
      fx4 v = xv[c];
      fx4 s4 = *reinterpret_cast<const fx4*>(sc1 + (sl + 16 * c) * 4);
      ss += v[0] * v[0] + v[1] * v[1] + v[2] * v[2] + v[3] * v[3];
      am = fmaxf(am, fmaxf(fmaxf(fabsf(v[0] * s4[0]), fabsf(v[1] * s4[1])),
                           fmaxf(fabsf(v[2] * s4[2]), fabsf(v[3] * s4[3]))));
    }
    if (sl < 4) {
      fx4 v = xv[12];
      fx4 s4 = *reinterpret_cast<const fx4*>(sc1 + (sl + 192) * 4);
      ss += v[0] * v[0] + v[1] * v[1] + v[2] * v[2] + v[3] * v[3];
      am = fmaxf(am, fmaxf(fmaxf(fabsf(v[0] * s4[0]), fabsf(v[1] * s4[1])),
                           fmaxf(fabsf(v[2] * s4[2]), fabsf(v[3] * s4[3]))));
    }
#pragma unroll
    for (int m = 1; m < 16; m <<= 1) {
      ss += __shfl_xor(ss, m, 64);
      am = fmaxf(am, __shfl_xor(am, m, 64));
    }
    const float denom = sqrtf(ss) * (1.0f / 28.0f) + 1e-8f;
    const float invd  = 1.0f / denom;
    const float cl    = fmaxf(am * invd, 1e-5f);
    const float gq    = (127.0f / cl) * invd;
    if (sl == 0) inv1[token] = cl * (1.0f / 127.0f);

    // ---- quantize from regs into LDS (packed int8) ----
#pragma unroll
    for (int c = 0; c < 12; ++c) {
      fx4 v = xv[c];
      fx4 s4 = *reinterpret_cast<const fx4*>(sc1 + (sl + 16 * c) * 4);
      int q0 = (int)fminf(fmaxf(rintf(v[0] * s4[0] * gq), -128.f), 127.f);
      int q1i = (int)fminf(fmaxf(rintf(v[1] * s4[1] * gq), -128.f), 127.f);
      int q2i = (int)fminf(fmaxf(rintf(v[2] * s4[2] * gq), -128.f), 127.f);
      int q3i = (int)fminf(fmaxf(rintf(v[3] * s4[3] * gq), -128.f), 127.f);
      unsigned p = (unsigned)(q0 & 255) | ((unsigned)(q1i & 255) << 8) |
                   ((unsigned)(q2i & 255) << 16) | ((unsigned)(q3i & 255) << 24);
      *reinterpret_cast<unsigned*>(&q1[token * 848 + (sl + 16 * c) * 4]) = p;
    }
    if (sl < 4) {
      fx4 v = xv[12];
      fx4 s4 = *reinterpret_cast<const fx4*>(sc1 + (sl + 192) * 4);
      int q0 = (int)fminf(fmaxf(rintf(v[0] * s4[0] * gq), -128.f), 127.f);
      int q1i = (int)fminf(fmaxf(rintf(v[1] * s4[1] * gq), -128.f), 127.f);
      int q2i = (int)fminf(fmaxf(rintf(v[2] * s4[2] * gq), -128.f), 127.f);
      int q3i = (int)fminf(fmaxf(rintf(v[3] * s4[3] * gq), -128.f), 127.f);
      unsigned p = (unsigned)(q0 & 255) | ((unsigned)(q1i & 255) << 8) |
                   ((unsigned)(q2i & 255) << 16) | ((unsigned)(q3i & 255) << 24);
      *reinterpret_cast<unsigned*>(&q1[token * 848 + (sl + 192) * 4]) = p;
    }

    // ---- prefetch next tile's x into the now-dead registers ----
    {
      const int ntile = tile + (int)gridDim.x;
      if (ntile < numTiles) {
        const float* rowp = x + (size_t)(ntile * 16 + token) * 784;
#pragma unroll
        for (int c = 0; c < 12; ++c)
          xv[c] = *reinterpret_cast<const fx4*>(rowp + (sl + 16 * c) * 4);
        if (sl < 4) xv[12] = *reinterpret_cast<const fx4*>(rowp + (sl + 192) * 4);
      }
    }

    sync_lds();  // BAR1: q1 ready (prefetch stays in flight)

    // ---- MFMA1: M=16, N=128 (wave wv -> cols wv*32..+31), K=832 ----
    ix4 acc0 = {0, 0, 0, 0}, acc1 = {0, 0, 0, 0};
    {
      const int8_t* b0p = t1 + (wv * 32 + sl) * 832;
      const int8_t* b1p = b0p + 16 * 832;
#pragma unroll 4
      for (int kk = 0; kk < 13; ++kk) {
        const int k0 = kk * 64 + g * 16;
        ix4 a  = *reinterpret_cast<const ix4*>(&q1[sl * 848 + k0]);
        ix4 b0 = *reinterpret_cast<const ix4*>(b0p + k0);
        ix4 b1 = *reinterpret_cast<const ix4*>(b1p + k0);
        acc0 = MFMA_I8(a, b0, acc0);
        acc1 = MFMA_I8(a, b1, acc1);
      }
    }
#pragma unroll
    for (int r = 0; r < 4; ++r) {
      const int tr = g * 4 + r;
      const float s = inv1[tr] * m1;
      h1[tr * 132 + wv * 32 + sl]      = fmaxf((float)acc0[r] * s, 0.f);
      h1[tr * 132 + wv * 32 + 16 + sl] = fmaxf((float)acc1[r] * s, 0.f);
    }
    sync_lds();  // BAR2: h1 ready

    // ---- layers 2+3: wave 0 only, zero extra barriers ----
    // Safe: wave 0 reads h1 (overwritten only after next BAR1, which needs
    // wave 0's arrival) and its private h2f; waves 1-3 write only q1 (read
    // phase for this tile finished before BAR2).
    if (wv == 0) {
      // lane (g,sl): token sl, channels g*16..+15 (k0) and 64+g*16..+15 (k1)
      const float* hrow = &h1[sl * 132];
      // pass 1: stats over this lane's 32 channels
      float ss2 = 0.f, am2 = 0.f;
#pragma unroll
      for (int half = 0; half < 2; ++half) {
        const int base = half * 64 + g * 16;
#pragma unroll
        for (int q = 0; q < 4; ++q) {
          fx4 v  = *reinterpret_cast<const fx4*>(hrow + base + q * 4);
          fx4 s4 = *reinterpret_cast<const fx4*>(sc2 + base + q * 4);
          ss2 += v[0]*v[0] + v[1]*v[1] + v[2]*v[2] + v[3]*v[3];
          am2 = fmaxf(am2, fmaxf(fmaxf(fabsf(v[0]*s4[0]), fabsf(v[1]*s4[1])),
                                 fmaxf(fabsf(v[2]*s4[2]), fabsf(v[3]*s4[3]))));
        }
      }
      // reduce across g (lane bits 4,5); lanes with same sl share token sl
      ss2 += __shfl_xor(ss2, 16, 64);
      am2 = fmaxf(am2, __shfl_xor(am2, 16, 64));
      ss2 += __shfl_xor(ss2, 32, 64);
      am2 = fmaxf(am2, __shfl_xor(am2, 32, 64));
      const float den2 = sqrtf(ss2) * 0.08838834764831845f + 1e-8f; // 1/sqrt(128)
      const float id2  = 1.0f / den2;
      const float cl2  = fmaxf(am2 * id2, 1e-5f);
      const float gq2  = (127.0f / cl2) * id2;
      const float i2self = cl2 * (1.0f / 127.0f);  // token sl dequant scale

      // pass 2: quantize straight into A-fragments (row-major == A-layout)
      ix4 a2f[2];
#pragma unroll
      for (int half = 0; half < 2; ++half) {
        const int base = half * 64 + g * 16;
#pragma unroll
        for (int q = 0; q < 4; ++q) {
          fx4 v  = *reinterpret_cast<const fx4*>(hrow + base + q * 4);
          fx4 s4 = *reinterpret_cast<const fx4*>(sc2 + base + q * 4);
          int c0 = (int)fminf(fmaxf(rintf(v[0] * s4[0] * gq2), -128.f), 127.f);
          int c1 = (int)fminf(fmaxf(rintf(v[1] * s4[1] * gq2), -128.f), 127.f);
          int c2 = (int)fminf(fmaxf(rintf(v[2] * s4[2] * gq2), -128.f), 127.f);
          int c3 = (int)fminf(fmaxf(rintf(v[3] * s4[3] * gq2), -128.f), 127.f);
          a2f[half][q] = (int)((unsigned)(c0 & 255) | ((unsigned)(c1 & 255) << 8) |
                               ((unsigned)(c2 & 255) << 16) | ((unsigned)(c3 & 255) << 24));
        }
      }

      // dequant scales for the tokens this lane's D rows cover
      float i2tok[4];
#pragma unroll
      for (int r = 0; r < 4; ++r) i2tok[r] = __shfl(i2self, 4 * g + r, 64);

      // MFMA2 per nt-block; immediately dequant+relu into h2f (low reg pressure)
      // D layout: lane (g,sl) -> token 4g+r, channel nt*16+sl
#pragma unroll
      for (int nt = 0; nt < 4; ++nt) {
        const int8_t* bp = t2 + (nt * 16 + sl) * 128 + g * 16;
        ix4 c = {0, 0, 0, 0};
        c = MFMA_I8(a2f[0], *reinterpret_cast<const ix4*>(bp), c);
        c = MFMA_I8(a2f[1], *reinterpret_cast<const ix4*>(bp + 64), c);
#pragma unroll
        for (int r = 0; r < 4; ++r)
          h2f[(4 * g + r) * 68 + nt * 16 + sl] =
              fmaxf((float)c[r] * i2tok[r] * m2, 0.f);
      }
      wave_lds_fence();  // same-wave write->read, no barrier needed

      // re-read token-major: lane (g,sl) = token sl, channels 16g..16g+15
      // (this IS MFMA3's A-fragment layout -> no transpose, no k-permutation)
      fx4 hv[4], s4v[4];
#pragma unroll
      for (int q = 0; q < 4; ++q) {
        hv[q]  = *reinterpret_cast<const fx4*>(&h2f[sl * 68 + g * 16 + q * 4]);
        s4v[q] = *reinterpret_cast<const fx4*>(sc3 + g * 16 + q * 4);
      }
      float ss3 = 0.f, am3 = 0.f;
#pragma unroll
      for (int q = 0; q < 4; ++q) {
        fx4 v = hv[q], s4 = s4v[q];
        ss3 += v[0]*v[0] + v[1]*v[1] + v[2]*v[2] + v[3]*v[3];
        am3 = fmaxf(am3, fmaxf(fmaxf(fabsf(v[0]*s4[0]), fabsf(v[1]*s4[1])),
                               fmaxf(fabsf(v[2]*s4[2]), fabsf(v[3]*s4[3]))));
      }
      ss3 += __shfl_xor(ss3, 16, 64);
      am3 = fmaxf(am3, __shfl_xor(am3, 16, 64));
      ss3 += __shfl_xor(ss3, 32, 64);
      am3 = fmaxf(am3, __shfl_xor(am3, 32, 64));
      const float den3 = sqrtf(ss3) * 0.125f + 1e-8f;  // 1/sqrt(64)
      const float id3  = 1.0f / den3;
      const float cl3  = fmaxf(am3 * id3, 1e-5f);
      const float gq3  = (127.0f / cl3) * id3;
      const float i3self = cl3 * (1.0f / 127.0f) * m3;  // token sl out scale

      // quant3 directly into the A-fragment
      ix4 a3;
#pragma unroll
      for (int q = 0; q < 4; ++q) {
        fx4 v = hv[q], s4 = s4v[q];
        int c0 = (int)fminf(fmaxf(rintf(v[0] * s4[0] * gq3), -128.f), 127.f);
        int c1 = (int)fminf(fmaxf(rintf(v[1] * s4[1] * gq3), -128.f), 127.f);
        int c2 = (int)fminf(fmaxf(rintf(v[2] * s4[2] * gq3), -128.f), 127.f);
        int c3 = (int)fminf(fmaxf(rintf(v[3] * s4[3] * gq3), -128.f), 127.f);
        a3[q] = (int)((unsigned)(c0 & 255) | ((unsigned)(c1 & 255) << 8) |
                      ((unsigned)(c2 & 255) << 16) | ((unsigned)(c3 & 255) << 24));
      }

      // MFMA3: M=16 tokens, N=16 (10 used), K=64; B[k=16g+j][n=sl] = t3[sl][16g+j]
      ix4 b3 = *reinterpret_cast<const ix4*>(t3 + sl * 64 + g * 16);
      ix4 acc3 = {0, 0, 0, 0};
      acc3 = MFMA_I8(a3, b3, acc3);

      // D: lane (g,sl) -> token 4g+r, col sl; need out-scale of token 4g+r
      float i3tok[4];
#pragma unroll
      for (int r = 0; r < 4; ++r) i3tok[r] = __shfl(i3self, 4 * g + r, 64);

      if (sl < 10) {
#pragma unroll
        for (int r = 0; r < 4; ++r)
          out[(size_t)(tile * 16 + 4 * g + r) * 10 + sl] = (float)acc3[r] * i3tok[r];
      }
    }
    // next iteration's q1 writes are safe: all waves passed BAR2 (q1 reads
    // done); h1 overwrite happens only after next BAR1 (wave-0 l23 reads done
    // by then, since BAR1 needs wave 0's arrival).
  }
}

// ---------------------------------------------------------------- launch
extern "C" void kernel_launch(void* const* d_in, const int* in_sizes, int n_in,
                              void* d_out, int out_size, void* d_ws, size_t ws_size,
                              hipStream_t stream) {
  const float* x  = (const float*)d_in[0];
  const float* w1 = (const float*)d_in[1];
  const float* s1 = (const float*)d_in[2];
  const float* w2 = (const float*)d_in[3];
  const float* s2 = (const float*)d_in[4];
  const float* w3 = (const float*)d_in[5];
  const float* s3 = (const float*)d_in[6];
  float* out = (float*)d_out;

  char* ws = (char*)d_ws;
  double* sums = (double*)ws;
  int8_t* t1   = (int8_t*)(ws + 1024);
  int8_t* t2   = (int8_t*)(ws + 107520);
  int8_t* t3   = (int8_t*)(ws + 115712);

  const int B = in_sizes[0] / 784;
  const int numTiles = B / 16;

  hipMemsetAsync(sums, 0, 3 * sizeof(double), stream);
  prep_mean<<<249, 256, 0, stream>>>(w1, w2, w3, sums);
  const int total_q = 128 * 832 + 64 * 128 + 16 * 64;  // 115712
  prep_quant<<<(total_q + 255) / 256, 256, 0, stream>>>(w1, w2, w3, sums, t1, t2, t3);
  const int grid1 = numTiles < 1024 ? numTiles : 1024;
  ffn_fused<<<grid1, 256, 0, stream>>>(x, s1, s2, s3, t1, t2, t3, sums, out, numTiles);
}

// Round 5
// 314.051 us; speedup vs baseline: 1.2342x; 1.2342x over previous
//
#include <hip/hip_runtime.h>
#include <stdint.h>

// BitNet-style fused 3-layer MLP for MI355X (gfx950) — round 7.
//
// Round-6 post-mortem (first real counters on our kernel): __launch_bounds__
// (256,4) made the compiler squeeze to VGPR=64 and SPILL the xv[13] prefetch
// -> WRITE_SIZE 111 MB (vs 2.6 MB ideal), FETCH +78 MB, ffn 172.7 us at 29%
// HBM / 12% VALU / 1.7% MFMA. Ladder: split 103us -> fused+prefetch no-cap
// 115us (VGPR>128, occupancy halved) -> fused capped 172us (spill).
// The persistent loop + register prefetch is what stacks xv[13] on top of
// the tail's registers. Round-7: NON-PERSISTENT one-shot blocks.
//   - grid = numTiles (4096); each block does one 16-token tile and exits.
//   - no prefetch regs; inter-tile latency hiding comes from other resident
//     blocks (3-4 blocks/CU). Clean liveness: xv dead at BAR1, MFMA accs
//     dead at BAR2, tail regs after -> compiler should fit ~110 VGPR, 0 spill.
//   - keeps the fusion win: single dispatch, no q2/inv2 HBM round-trip.
//   - plain __launch_bounds__(256): no min-wave constraint, no spill pressure.
//
// ws layout (offsets mult of 256):
//   0        double sums[3]
//   1024     t1:  128 x 832 int8 ternary w1 (K 784->832 zero-pad)   106496 B
//   107520   t2:  64 x 128 int8 ternary w2                            8192 B
//   115712   t3:  16 x 64  int8 ternary w3, rows 10..15 = 0           1024 B

typedef int   ix4 __attribute__((ext_vector_type(4)));
typedef float fx4 __attribute__((ext_vector_type(4)));

#define MFMA_I8(a, b, c) __builtin_amdgcn_mfma_i32_16x16x64_i8((a), (b), (c), 0, 0, 0)

// Barrier that waits LDS ops only; global loads stay in flight.
__device__ __forceinline__ void sync_lds() {
  asm volatile("s_waitcnt lgkmcnt(0)" ::: "memory");
  __builtin_amdgcn_s_barrier();
}
__device__ __forceinline__ void wave_lds_fence() {
  asm volatile("s_waitcnt lgkmcnt(0)" ::: "memory");
}

// ---------------------------------------------------------------- prep 1
__global__ __launch_bounds__(256) void prep_mean(
    const float* __restrict__ w1, const float* __restrict__ w2,
    const float* __restrict__ w3, double* __restrict__ sums) {
  __shared__ double red[256];
  const int b = blockIdx.x;
  const float* w; int n, nb, bb, which;
  if (b < 240)      { w = w1; n = 128 * 784; nb = 240; bb = b;       which = 0; }
  else if (b < 248) { w = w2; n = 64 * 128;  nb = 8;   bb = b - 240; which = 1; }
  else              { w = w3; n = 10 * 64;   nb = 1;   bb = 0;       which = 2; }
  double s = 0.0;
  for (int i = bb * 256 + (int)threadIdx.x; i < n; i += nb * 256)
    s += (double)fabsf(w[i]);
  red[threadIdx.x] = s;
  __syncthreads();
  for (int off = 128; off > 0; off >>= 1) {
    if ((int)threadIdx.x < off) red[threadIdx.x] += red[threadIdx.x + off];
    __syncthreads();
  }
  if (threadIdx.x == 0) atomicAdd(&sums[which], red[0]);
}

// ---------------------------------------------------------------- prep 2
__global__ __launch_bounds__(256) void prep_quant(
    const float* __restrict__ w1, const float* __restrict__ w2,
    const float* __restrict__ w3, const double* __restrict__ sums,
    int8_t* __restrict__ t1, int8_t* __restrict__ t2,
    int8_t* __restrict__ t3) {
  const int idx = blockIdx.x * 256 + (int)threadIdx.x;
  const float s1 = 1.0f / fmaxf((float)(sums[0] * (1.0 / (128.0 * 784.0))), 1e-5f);
  const float s2 = 1.0f / fmaxf((float)(sums[1] * (1.0 / (64.0 * 128.0))), 1e-5f);
  const float s3 = 1.0f / fmaxf((float)(sums[2] * (1.0 / (10.0 * 64.0))), 1e-5f);
  if (idx < 128 * 832) {
    const int n = idx / 832, k = idx - n * 832;
    float v = 0.f;
    if (k < 784) v = fminf(fmaxf(rintf(w1[n * 784 + k] * s1), -1.f), 1.f);
    t1[idx] = (int8_t)(int)v;
  } else if (idx < 128 * 832 + 64 * 128) {
    const int i = idx - 128 * 832;
    t2[i] = (int8_t)(int)fminf(fmaxf(rintf(w2[i] * s2), -1.f), 1.f);
  } else if (idx < 128 * 832 + 64 * 128 + 16 * 64) {
    const int i = idx - (128 * 832 + 64 * 128);
    const int n = i >> 6, k = i & 63;
    float v = 0.f;
    if (n < 10) v = fminf(fmaxf(rintf(w3[n * 64 + k] * s3), -1.f), 1.f);
    t3[i] = (int8_t)(int)v;
  }
}

// ---------------------------------------------------------------- fused ffn
// One-shot: block = one 16-token tile. Lane roles: wv=wave, g=l>>4, sl=l&15;
// L1 quant token = wv*4+g. i8 MFMA A: A[m=sl][k=64kk+16g+j]; D[4g+r][sl].
// After BAR2, wave 0 alone runs layers 2+3 in-wave; waves 1-3 exit.
__global__ __launch_bounds__(256)
void ffn_fused(
    const float* __restrict__ x,
    const float* __restrict__ sc1, const float* __restrict__ sc2,
    const float* __restrict__ sc3,
    const int8_t* __restrict__ t1, const int8_t* __restrict__ t2,
    const int8_t* __restrict__ t3, const double* __restrict__ sums,
    float* __restrict__ out) {
  __shared__ int8_t q1[16 * 848];   // 13.6 KB
  __shared__ float  h1[16 * 132];   // 8.4 KB
  __shared__ float  inv1[16];
  __shared__ float  h2f[16 * 68];   // 4.3 KB, wave-0 l2-output buffer

  const int tid = threadIdx.x;
  const int l   = tid & 63;
  const int wv  = tid >> 6;
  const int g   = l >> 4;
  const int sl  = l & 15;
  const int token = wv * 4 + g;
  const int tile  = blockIdx.x;

  const float m1 = fmaxf((float)(sums[0] * (1.0 / (128.0 * 784.0))), 1e-5f);

  // zero q1's K-pad [784,832)
  if (tid < 192) {
    const int t = tid / 12, c = tid - (tid / 12) * 12;
    *reinterpret_cast<unsigned*>(&q1[t * 848 + 784 + c * 4]) = 0u;
  }

  // ---- load this tile's x rows (16 lanes per token, 49 floats/lane) ----
  fx4 xv[13];
  {
    const float* rowp = x + (size_t)(tile * 16 + token) * 784;
#pragma unroll
    for (int c = 0; c < 12; ++c)
      xv[c] = *reinterpret_cast<const fx4*>(rowp + (sl + 16 * c) * 4);
    if (sl < 4) xv[12] = *reinterpret_cast<const fx4*>(rowp + (sl + 192) * 4);
  }

  // ---- stats: sumsq(x) + max|sc1*x| ----
  float ss = 0.f, am = 0.f;
#pragma unroll
  for (int c = 0; c < 12; ++c) {
    fx4 v = xv[c];
    fx4 s4 = *reinterpret_cast<const fx4*>(sc1 + (sl + 16 * c) * 4);
    ss += v[0] * v[0] + v[1] * v[1] + v[2] * v[2] + v[3] * v[3];
    am = fmaxf(am, fmaxf(fmaxf(fabsf(v[0] * s4[0]), fabsf(v[1] * s4[1])),
                         fmaxf(fabsf(v[2] * s4[2]), fabsf(v[3] * s4[3]))));
  }
  if (sl < 4) {
    fx4 v = xv[12];
    fx4 s4 = *reinterpret_cast<const fx4*>(sc1 + (sl + 192) * 4);
    ss += v[0] * v[0] + v[1] * v[1] + v[2] * v[2] + v[3] * v[3];
    am = fmaxf(am, fmaxf(fmaxf(fabsf(v[0] * s4[0]), fabsf(v[1] * s4[1])),
                         fmaxf(fabsf(v[2] * s4[2]), fabsf(v[3] * s4[3]))));
  }
#pragma unroll
  for (int m = 1; m < 16; m <<= 1) {
    ss += __shfl_xor(ss, m, 64);
    am = fmaxf(am, __shfl_xor(am, m, 64));
  }
  const float denom = sqrtf(ss) * (1.0f / 28.0f) + 1e-8f;
  const float invd  = 1.0f / denom;
  const float cl    = fmaxf(am * invd, 1e-5f);
  const float gq    = (127.0f / cl) * invd;
  if (sl == 0) inv1[token] = cl * (1.0f / 127.0f);

  // ---- quantize from regs into LDS (packed int8) ----
#pragma unroll
  for (int c = 0; c < 12; ++c) {
    fx4 v = xv[c];
    fx4 s4 = *reinterpret_cast<const fx4*>(sc1 + (sl + 16 * c) * 4);
    int q0 = (int)fminf(fmaxf(rintf(v[0] * s4[0] * gq), -128.f), 127.f);
    int q1i = (int)fminf(fmaxf(rintf(v[1] * s4[1] * gq), -128.f), 127.f);
    int q2i = (int)fminf(fmaxf(rintf(v[2] * s4[2] * gq), -128.f), 127.f);
    int q3i = (int)fminf(fmaxf(rintf(v[3] * s4[3] * gq), -128.f), 127.f);
    unsigned p = (unsigned)(q0 & 255) | ((unsigned)(q1i & 255) << 8) |
                 ((unsigned)(q2i & 255) << 16) | ((unsigned)(q3i & 255) << 24);
    *reinterpret_cast<unsigned*>(&q1[token * 848 + (sl + 16 * c) * 4]) = p;
  }
  if (sl < 4) {
    fx4 v = xv[12];
    fx4 s4 = *reinterpret_cast<const fx4*>(sc1 + (sl + 192) * 4);
    int q0 = (int)fminf(fmaxf(rintf(v[0] * s4[0] * gq), -128.f), 127.f);
    int q1i = (int)fminf(fmaxf(rintf(v[1] * s4[1] * gq), -128.f), 127.f);
    int q2i = (int)fminf(fmaxf(rintf(v[2] * s4[2] * gq), -128.f), 127.f);
    int q3i = (int)fminf(fmaxf(rintf(v[3] * s4[3] * gq), -128.f), 127.f);
    unsigned p = (unsigned)(q0 & 255) | ((unsigned)(q1i & 255) << 8) |
                 ((unsigned)(q2i & 255) << 16) | ((unsigned)(q3i & 255) << 24);
    *reinterpret_cast<unsigned*>(&q1[token * 848 + (sl + 192) * 4]) = p;
  }

  sync_lds();  // BAR1: q1 ready

  // ---- MFMA1: M=16, N=128 (wave wv -> cols wv*32..+31), K=832 ----
  ix4 acc0 = {0, 0, 0, 0}, acc1 = {0, 0, 0, 0};
  {
    const int8_t* b0p = t1 + (wv * 32 + sl) * 832;
    const int8_t* b1p = b0p + 16 * 832;
#pragma unroll 4
    for (int kk = 0; kk < 13; ++kk) {
      const int k0 = kk * 64 + g * 16;
      ix4 a  = *reinterpret_cast<const ix4*>(&q1[sl * 848 + k0]);
      ix4 b0 = *reinterpret_cast<const ix4*>(b0p + k0);
      ix4 b1 = *reinterpret_cast<const ix4*>(b1p + k0);
      acc0 = MFMA_I8(a, b0, acc0);
      acc1 = MFMA_I8(a, b1, acc1);
    }
  }
#pragma unroll
  for (int r = 0; r < 4; ++r) {
    const int tr = g * 4 + r;
    const float s = inv1[tr] * m1;
    h1[tr * 132 + wv * 32 + sl]      = fmaxf((float)acc0[r] * s, 0.f);
    h1[tr * 132 + wv * 32 + 16 + sl] = fmaxf((float)acc1[r] * s, 0.f);
  }
  sync_lds();  // BAR2: h1 ready

  // ---- layers 2+3: wave 0 only; waves 1-3 exit ----
  if (wv == 0) {
    const float m2 = fmaxf((float)(sums[1] * (1.0 / (64.0 * 128.0))), 1e-5f);
    const float m3 = fmaxf((float)(sums[2] * (1.0 / (10.0 * 64.0))), 1e-5f);

    // lane (g,sl): token sl, channels g*16..+15 (k0) and 64+g*16..+15 (k1)
    const float* hrow = &h1[sl * 132];
    // pass 1: stats over this lane's 32 channels
    float ss2 = 0.f, am2 = 0.f;
#pragma unroll
    for (int half = 0; half < 2; ++half) {
      const int base = half * 64 + g * 16;
#pragma unroll
      for (int q = 0; q < 4; ++q) {
        fx4 v  = *reinterpret_cast<const fx4*>(hrow + base + q * 4);
        fx4 s4 = *reinterpret_cast<const fx4*>(sc2 + base + q * 4);
        ss2 += v[0]*v[0] + v[1]*v[1] + v[2]*v[2] + v[3]*v[3];
        am2 = fmaxf(am2, fmaxf(fmaxf(fabsf(v[0]*s4[0]), fabsf(v[1]*s4[1])),
                               fmaxf(fabsf(v[2]*s4[2]), fabsf(v[3]*s4[3]))));
      }
    }
    // reduce across g (lane bits 4,5); lanes with same sl share token sl
    ss2 += __shfl_xor(ss2, 16, 64);
    am2 = fmaxf(am2, __shfl_xor(am2, 16, 64));
    ss2 += __shfl_xor(ss2, 32, 64);
    am2 = fmaxf(am2, __shfl_xor(am2, 32, 64));
    const float den2 = sqrtf(ss2) * 0.08838834764831845f + 1e-8f; // 1/sqrt(128)
    const float id2  = 1.0f / den2;
    const float cl2  = fmaxf(am2 * id2, 1e-5f);
    const float gq2  = (127.0f / cl2) * id2;
    const float i2self = cl2 * (1.0f / 127.0f);  // token sl dequant scale

    // pass 2: quantize straight into A-fragments (row-major == A-layout)
    ix4 a2f[2];
#pragma unroll
    for (int half = 0; half < 2; ++half) {
      const int base = half * 64 + g * 16;
#pragma unroll
      for (int q = 0; q < 4; ++q) {
        fx4 v  = *reinterpret_cast<const fx4*>(hrow + base + q * 4);
        fx4 s4 = *reinterpret_cast<const fx4*>(sc2 + base + q * 4);
        int c0 = (int)fminf(fmaxf(rintf(v[0] * s4[0] * gq2), -128.f), 127.f);
        int c1 = (int)fminf(fmaxf(rintf(v[1] * s4[1] * gq2), -128.f), 127.f);
        int c2 = (int)fminf(fmaxf(rintf(v[2] * s4[2] * gq2), -128.f), 127.f);
        int c3 = (int)fminf(fmaxf(rintf(v[3] * s4[3] * gq2), -128.f), 127.f);
        a2f[half][q] = (int)((unsigned)(c0 & 255) | ((unsigned)(c1 & 255) << 8) |
                             ((unsigned)(c2 & 255) << 16) | ((unsigned)(c3 & 255) << 24));
      }
    }

    // dequant scales for the tokens this lane's D rows cover
    float i2tok[4];
#pragma unroll
    for (int r = 0; r < 4; ++r) i2tok[r] = __shfl(i2self, 4 * g + r, 64);

    // MFMA2 per nt-block; immediately dequant+relu into h2f (low reg pressure)
    // D layout: lane (g,sl) -> token 4g+r, channel nt*16+sl
#pragma unroll
    for (int nt = 0; nt < 4; ++nt) {
      const int8_t* bp = t2 + (nt * 16 + sl) * 128 + g * 16;
      ix4 c = {0, 0, 0, 0};
      c = MFMA_I8(a2f[0], *reinterpret_cast<const ix4*>(bp), c);
      c = MFMA_I8(a2f[1], *reinterpret_cast<const ix4*>(bp + 64), c);
#pragma unroll
      for (int r = 0; r < 4; ++r)
        h2f[(4 * g + r) * 68 + nt * 16 + sl] =
            fmaxf((float)c[r] * i2tok[r] * m2, 0.f);
    }
    wave_lds_fence();  // same-wave write->read, no barrier needed

    // re-read token-major: lane (g,sl) = token sl, channels 16g..16g+15
    // (this IS MFMA3's A-fragment layout -> no transpose, no k-permutation)
    fx4 hv[4], s4v[4];
#pragma unroll
    for (int q = 0; q < 4; ++q) {
      hv[q]  = *reinterpret_cast<const fx4*>(&h2f[sl * 68 + g * 16 + q * 4]);
      s4v[q] = *reinterpret_cast<const fx4*>(sc3 + g * 16 + q * 4);
    }
    float ss3 = 0.f, am3 = 0.f;
#pragma unroll
    for (int q = 0; q < 4; ++q) {
      fx4 v = hv[q], s4 = s4v[q];
      ss3 += v[0]*v[0] + v[1]*v[1] + v[2]*v[2] + v[3]*v[3];
      am3 = fmaxf(am3, fmaxf(fmaxf(fabsf(v[0]*s4[0]), fabsf(v[1]*s4[1])),
                             fmaxf(fabsf(v[2]*s4[2]), fabsf(v[3]*s4[3]))));
    }
    ss3 += __shfl_xor(ss3, 16, 64);
    am3 = fmaxf(am3, __shfl_xor(am3, 16, 64));
    ss3 += __shfl_xor(ss3, 32, 64);
    am3 = fmaxf(am3, __shfl_xor(am3, 32, 64));
    const float den3 = sqrtf(ss3) * 0.125f + 1e-8f;  // 1/sqrt(64)
    const float id3  = 1.0f / den3;
    const float cl3  = fmaxf(am3 * id3, 1e-5f);
    const float gq3  = (127.0f / cl3) * id3;
    const float i3self = cl3 * (1.0f / 127.0f) * m3;  // token sl out scale

    // quant3 directly into the A-fragment
    ix4 a3;
#pragma unroll
    for (int q = 0; q < 4; ++q) {
      fx4 v = hv[q], s4 = s4v[q];
      int c0 = (int)fminf(fmaxf(rintf(v[0] * s4[0] * gq3), -128.f), 127.f);
      int c1 = (int)fminf(fmaxf(rintf(v[1] * s4[1] * gq3), -128.f), 127.f);
      int c2 = (int)fminf(fmaxf(rintf(v[2] * s4[2] * gq3), -128.f), 127.f);
      int c3 = (int)fminf(fmaxf(rintf(v[3] * s4[3] * gq3), -128.f), 127.f);
      a3[q] = (int)((unsigned)(c0 & 255) | ((unsigned)(c1 & 255) << 8) |
                    ((unsigned)(c2 & 255) << 16) | ((unsigned)(c3 & 255) << 24));
    }

    // MFMA3: M=16 tokens, N=16 (10 used), K=64; B[k=16g+j][n=sl] = t3[sl][16g+j]
    ix4 b3 = *reinterpret_cast<const ix4*>(t3 + sl * 64 + g * 16);
    ix4 acc3 = {0, 0, 0, 0};
    acc3 = MFMA_I8(a3, b3, acc3);

    // D: lane (g,sl) -> token 4g+r, col sl; need out-scale of token 4g+r
    float i3tok[4];
#pragma unroll
    for (int r = 0; r < 4; ++r) i3tok[r] = __shfl(i3self, 4 * g + r, 64);

    if (sl < 10) {
#pragma unroll
      for (int r = 0; r < 4; ++r)
        out[(size_t)(tile * 16 + 4 * g + r) * 10 + sl] = (float)acc3[r] * i3tok[r];
    }
  }
}

// ---------------------------------------------------------------- launch
extern "C" void kernel_launch(void* const* d_in, const int* in_sizes, int n_in,
                              void* d_out, int out_size, void* d_ws, size_t ws_size,
                              hipStream_t stream) {
  const float* x  = (const float*)d_in[0];
  const float* w1 = (const float*)d_in[1];
  const float* s1 = (const float*)d_in[2];
  const float* w2 = (const float*)d_in[3];
  const float* s2 = (const float*)d_in[4];
  const float* w3 = (const float*)d_in[5];
  const float* s3 = (const float*)d_in[6];
  float* out = (float*)d_out;

  char* ws = (char*)d_ws;
  double* sums = (double*)ws;
  int8_t* t1   = (int8_t*)(ws + 1024);
  int8_t* t2   = (int8_t*)(ws + 107520);
  int8_t* t3   = (int8_t*)(ws + 115712);

  const int B = in_sizes[0] / 784;
  const int numTiles = B / 16;

  hipMemsetAsync(sums, 0, 3 * sizeof(double), stream);
  prep_mean<<<249, 256, 0, stream>>>(w1, w2, w3, sums);
  const int total_q = 128 * 832 + 64 * 128 + 16 * 64;  // 115712
  prep_quant<<<(total_q + 255) / 256, 256, 0, stream>>>(w1, w2, w3, sums, t1, t2, t3);
  ffn_fused<<<numTiles, 256, 0, stream>>>(x, s1, s2, s3, t1, t2, t3, sums, out);
}

// Round 6
// 308.385 us; speedup vs baseline: 1.2569x; 1.0184x over previous
//
#include <hip/hip_runtime.h>
#include <stdint.h>

// BitNet-style fused 3-layer MLP for MI355X (gfx950) — round 8.
//
// Round-7 post-mortem: non-persistent one-shot fused kernel WORKED —
// spill gone, ffn below the ~120us poison fills (out of top-5), total
// 314.05us = best measured. Top-5 is 100% harness fills (~240us/iter,
// fixed). Remaining controllable slack ~25us: ffn latency-hiding (~4
// blocks/CU resident, VGPR-limited) + dispatch overhead.
// Round-8 (low-risk shavings):
//   1. memset dispatch removed: prep_mean writes per-block PARTIAL sums
//      (no atomics -> no zero-init needed); prep_quant wave-reduces the
//      249 partials and publishes finals[3] for ffn. 4 dispatches -> 3.
//   2. h2f unioned onto q1's LDS (q1 dead after BAR2, h2f born after):
//      LDS 26.6 -> ~22.1 KB -> +1 resident block/CU -> better x-latency
//      hiding via TLP.
//
// ws layout:
//   0      part[256] doubles: per-block |w| partial sums (249 used)  2048 B
//   2048   finals[3] doubles: total |w| sums (by prep_quant blk 0)     24 B
//   4096   t1:  128 x 832 int8 ternary w1 (K 784->832 zero-pad)    106496 B
//   110592 t2:  64 x 128 int8 ternary w2                             8192 B
//   118784 t3:  16 x 64  int8 ternary w3, rows 10..15 = 0            1024 B

typedef int   ix4 __attribute__((ext_vector_type(4)));
typedef float fx4 __attribute__((ext_vector_type(4)));

#define MFMA_I8(a, b, c) __builtin_amdgcn_mfma_i32_16x16x64_i8((a), (b), (c), 0, 0, 0)

// Barrier that waits LDS ops only; global loads stay in flight.
__device__ __forceinline__ void sync_lds() {
  asm volatile("s_waitcnt lgkmcnt(0)" ::: "memory");
  __builtin_amdgcn_s_barrier();
}
__device__ __forceinline__ void wave_lds_fence() {
  asm volatile("s_waitcnt lgkmcnt(0)" ::: "memory");
}

// ---------------------------------------------------------------- prep 1
// 249 blocks; block b writes its partial |w| sum to part[b]. No atomics,
// no zero-init required (every used slot is written unconditionally).
__global__ __launch_bounds__(256) void prep_mean(
    const float* __restrict__ w1, const float* __restrict__ w2,
    const float* __restrict__ w3, double* __restrict__ part) {
  __shared__ double red[256];
  const int b = blockIdx.x;
  const float* w; int n, nb, bb;
  if (b < 240)      { w = w1; n = 128 * 784; nb = 240; bb = b;       }
  else if (b < 248) { w = w2; n = 64 * 128;  nb = 8;   bb = b - 240; }
  else              { w = w3; n = 10 * 64;   nb = 1;   bb = 0;       }
  double s = 0.0;
  for (int i = bb * 256 + (int)threadIdx.x; i < n; i += nb * 256)
    s += (double)fabsf(w[i]);
  red[threadIdx.x] = s;
  __syncthreads();
  for (int off = 128; off > 0; off >>= 1) {
    if ((int)threadIdx.x < off) red[threadIdx.x] += red[threadIdx.x + off];
    __syncthreads();
  }
  if (threadIdx.x == 0) part[b] = red[0];
}

// ---------------------------------------------------------------- prep 2
// Reduces part[] (w1: 0..239, w2: 240..247, w3: 248) in one wave, then
// ternary-quantizes all three weight tensors. Block 0 publishes finals[3].
__global__ __launch_bounds__(256) void prep_quant(
    const float* __restrict__ w1, const float* __restrict__ w2,
    const float* __restrict__ w3, const double* __restrict__ part,
    double* __restrict__ finals,
    int8_t* __restrict__ t1, int8_t* __restrict__ t2,
    int8_t* __restrict__ t3) {
  __shared__ double sred[3];
  if (threadIdx.x < 64) {
    const int l = threadIdx.x;
    double a = part[l] + part[l + 64] + part[l + 128];
    if (l < 48) a += part[l + 192];
#pragma unroll
    for (int m = 1; m < 64; m <<= 1) a += __shfl_xor(a, m, 64);
    double b = (l < 8) ? part[240 + l] : 0.0;
#pragma unroll
    for (int m = 1; m < 8; m <<= 1) b += __shfl_xor(b, m, 64);
    if (l == 0) {
      sred[0] = a; sred[1] = b; sred[2] = part[248];
      if (blockIdx.x == 0) { finals[0] = a; finals[1] = b; finals[2] = part[248]; }
    }
  }
  __syncthreads();
  const float s1 = 1.0f / fmaxf((float)(sred[0] * (1.0 / (128.0 * 784.0))), 1e-5f);
  const float s2 = 1.0f / fmaxf((float)(sred[1] * (1.0 / (64.0 * 128.0))), 1e-5f);
  const float s3 = 1.0f / fmaxf((float)(sred[2] * (1.0 / (10.0 * 64.0))), 1e-5f);

  const int idx = blockIdx.x * 256 + (int)threadIdx.x;
  if (idx < 128 * 832) {
    const int n = idx / 832, k = idx - n * 832;
    float v = 0.f;
    if (k < 784) v = fminf(fmaxf(rintf(w1[n * 784 + k] * s1), -1.f), 1.f);
    t1[idx] = (int8_t)(int)v;
  } else if (idx < 128 * 832 + 64 * 128) {
    const int i = idx - 128 * 832;
    t2[i] = (int8_t)(int)fminf(fmaxf(rintf(w2[i] * s2), -1.f), 1.f);
  } else if (idx < 128 * 832 + 64 * 128 + 16 * 64) {
    const int i = idx - (128 * 832 + 64 * 128);
    const int n = i >> 6, k = i & 63;
    float v = 0.f;
    if (n < 10) v = fminf(fmaxf(rintf(w3[n * 64 + k] * s3), -1.f), 1.f);
    t3[i] = (int8_t)(int)v;
  }
}

// ---------------------------------------------------------------- fused ffn
// One-shot: block = one 16-token tile. Lane roles: wv=wave, g=l>>4, sl=l&15;
// L1 quant token = wv*4+g. i8 MFMA A: A[m=sl][k=64kk+16g+j]; D[4g+r][sl].
// After BAR2, wave 0 alone runs layers 2+3 in-wave; waves 1-3 exit.
__global__ __launch_bounds__(256)
void ffn_fused(
    const float* __restrict__ x,
    const float* __restrict__ sc1, const float* __restrict__ sc2,
    const float* __restrict__ sc3,
    const int8_t* __restrict__ t1, const int8_t* __restrict__ t2,
    const int8_t* __restrict__ t3, const double* __restrict__ finals,
    float* __restrict__ out) {
  // q1 is dead after BAR2; the wave-0 l2-output buffer h2f reuses its space.
  __shared__ alignas(16) int8_t q1[16 * 848];   // 13.6 KB (also h2f after BAR2)
  __shared__ float  h1[16 * 132];               // 8.4 KB
  __shared__ float  inv1[16];
  float* h2f = reinterpret_cast<float*>(q1);    // 16*68 floats, 4.3 KB used

  const int tid = threadIdx.x;
  const int l   = tid & 63;
  const int wv  = tid >> 6;
  const int g   = l >> 4;
  const int sl  = l & 15;
  const int token = wv * 4 + g;
  const int tile  = blockIdx.x;

  const float m1 = fmaxf((float)(finals[0] * (1.0 / (128.0 * 784.0))), 1e-5f);

  // zero q1's K-pad [784,832)
  if (tid < 192) {
    const int t = tid / 12, c = tid - (tid / 12) * 12;
    *reinterpret_cast<unsigned*>(&q1[t * 848 + 784 + c * 4]) = 0u;
  }

  // ---- load this tile's x rows (16 lanes per token, 49 floats/lane) ----
  fx4 xv[13];
  {
    const float* rowp = x + (size_t)(tile * 16 + token) * 784;
#pragma unroll
    for (int c = 0; c < 12; ++c)
      xv[c] = *reinterpret_cast<const fx4*>(rowp + (sl + 16 * c) * 4);
    if (sl < 4) xv[12] = *reinterpret_cast<const fx4*>(rowp + (sl + 192) * 4);
  }

  // ---- stats: sumsq(x) + max|sc1*x| ----
  float ss = 0.f, am = 0.f;
#pragma unroll
  for (int c = 0; c < 12; ++c) {
    fx4 v = xv[c];
    fx4 s4 = *reinterpret_cast<const fx4*>(sc1 + (sl + 16 * c) * 4);
    ss += v[0] * v[0] + v[1] * v[1] + v[2] * v[2] + v[3] * v[3];
    am = fmaxf(am, fmaxf(fmaxf(fabsf(v[0] * s4[0]), fabsf(v[1] * s4[1])),
                         fmaxf(fabsf(v[2] * s4[2]), fabsf(v[3] * s4[3]))));
  }
  if (sl < 4) {
    fx4 v = xv[12];
    fx4 s4 = *reinterpret_cast<const fx4*>(sc1 + (sl + 192) * 4);
    ss += v[0] * v[0] + v[1] * v[1] + v[2] * v[2] + v[3] * v[3];
    am = fmaxf(am, fmaxf(fmaxf(fabsf(v[0] * s4[0]), fabsf(v[1] * s4[1])),
                         fmaxf(fabsf(v[2] * s4[2]), fabsf(v[3] * s4[3]))));
  }
#pragma unroll
  for (int m = 1; m < 16; m <<= 1) {
    ss += __shfl_xor(ss, m, 64);
    am = fmaxf(am, __shfl_xor(am, m, 64));
  }
  const float denom = sqrtf(ss) * (1.0f / 28.0f) + 1e-8f;
  const float invd  = 1.0f / denom;
  const float cl    = fmaxf(am * invd, 1e-5f);
  const float gq    = (127.0f / cl) * invd;
  if (sl == 0) inv1[token] = cl * (1.0f / 127.0f);

  // ---- quantize from regs into LDS (packed int8) ----
#pragma unroll
  for (int c = 0; c < 12; ++c) {
    fx4 v = xv[c];
    fx4 s4 = *reinterpret_cast<const fx4*>(sc1 + (sl + 16 * c) * 4);
    int q0 = (int)fminf(fmaxf(rintf(v[0] * s4[0] * gq), -128.f), 127.f);
    int q1i = (int)fminf(fmaxf(rintf(v[1] * s4[1] * gq), -128.f), 127.f);
    int q2i = (int)fminf(fmaxf(rintf(v[2] * s4[2] * gq), -128.f), 127.f);
    int q3i = (int)fminf(fmaxf(rintf(v[3] * s4[3] * gq), -128.f), 127.f);
    unsigned p = (unsigned)(q0 & 255) | ((unsigned)(q1i & 255) << 8) |
                 ((unsigned)(q2i & 255) << 16) | ((unsigned)(q3i & 255) << 24);
    *reinterpret_cast<unsigned*>(&q1[token * 848 + (sl + 16 * c) * 4]) = p;
  }
  if (sl < 4) {
    fx4 v = xv[12];
    fx4 s4 = *reinterpret_cast<const fx4*>(sc1 + (sl + 192) * 4);
    int q0 = (int)fminf(fmaxf(rintf(v[0] * s4[0] * gq), -128.f), 127.f);
    int q1i = (int)fminf(fmaxf(rintf(v[1] * s4[1] * gq), -128.f), 127.f);
    int q2i = (int)fminf(fmaxf(rintf(v[2] * s4[2] * gq), -128.f), 127.f);
    int q3i = (int)fminf(fmaxf(rintf(v[3] * s4[3] * gq), -128.f), 127.f);
    unsigned p = (unsigned)(q0 & 255) | ((unsigned)(q1i & 255) << 8) |
                 ((unsigned)(q2i & 255) << 16) | ((unsigned)(q3i & 255) << 24);
    *reinterpret_cast<unsigned*>(&q1[token * 848 + (sl + 192) * 4]) = p;
  }

  sync_lds();  // BAR1: q1 ready

  // ---- MFMA1: M=16, N=128 (wave wv -> cols wv*32..+31), K=832 ----
  ix4 acc0 = {0, 0, 0, 0}, acc1 = {0, 0, 0, 0};
  {
    const int8_t* b0p = t1 + (wv * 32 + sl) * 832;
    const int8_t* b1p = b0p + 16 * 832;
#pragma unroll 4
    for (int kk = 0; kk < 13; ++kk) {
      const int k0 = kk * 64 + g * 16;
      ix4 a  = *reinterpret_cast<const ix4*>(&q1[sl * 848 + k0]);
      ix4 b0 = *reinterpret_cast<const ix4*>(b0p + k0);
      ix4 b1 = *reinterpret_cast<const ix4*>(b1p + k0);
      acc0 = MFMA_I8(a, b0, acc0);
      acc1 = MFMA_I8(a, b1, acc1);
    }
  }
#pragma unroll
  for (int r = 0; r < 4; ++r) {
    const int tr = g * 4 + r;
    const float s = inv1[tr] * m1;
    h1[tr * 132 + wv * 32 + sl]      = fmaxf((float)acc0[r] * s, 0.f);
    h1[tr * 132 + wv * 32 + 16 + sl] = fmaxf((float)acc1[r] * s, 0.f);
  }
  sync_lds();  // BAR2: h1 ready; q1 now dead -> its LDS becomes h2f

  // ---- layers 2+3: wave 0 only; waves 1-3 exit ----
  if (wv == 0) {
    const float m2 = fmaxf((float)(finals[1] * (1.0 / (64.0 * 128.0))), 1e-5f);
    const float m3 = fmaxf((float)(finals[2] * (1.0 / (10.0 * 64.0))), 1e-5f);

    // lane (g,sl): token sl, channels g*16..+15 (k0) and 64+g*16..+15 (k1)
    const float* hrow = &h1[sl * 132];
    // pass 1: stats over this lane's 32 channels
    float ss2 = 0.f, am2 = 0.f;
#pragma unroll
    for (int half = 0; half < 2; ++half) {
      const int base = half * 64 + g * 16;
#pragma unroll
      for (int q = 0; q < 4; ++q) {
        fx4 v  = *reinterpret_cast<const fx4*>(hrow + base + q * 4);
        fx4 s4 = *reinterpret_cast<const fx4*>(sc2 + base + q * 4);
        ss2 += v[0]*v[0] + v[1]*v[1] + v[2]*v[2] + v[3]*v[3];
        am2 = fmaxf(am2, fmaxf(fmaxf(fabsf(v[0]*s4[0]), fabsf(v[1]*s4[1])),
                               fmaxf(fabsf(v[2]*s4[2]), fabsf(v[3]*s4[3]))));
      }
    }
    // reduce across g (lane bits 4,5); lanes with same sl share token sl
    ss2 += __shfl_xor(ss2, 16, 64);
    am2 = fmaxf(am2, __shfl_xor(am2, 16, 64));
    ss2 += __shfl_xor(ss2, 32, 64);
    am2 = fmaxf(am2, __shfl_xor(am2, 32, 64));
    const float den2 = sqrtf(ss2) * 0.08838834764831845f + 1e-8f; // 1/sqrt(128)
    const float id2  = 1.0f / den2;
    const float cl2  = fmaxf(am2 * id2, 1e-5f);
    const float gq2  = (127.0f / cl2) * id2;
    const float i2self = cl2 * (1.0f / 127.0f);  // token sl dequant scale

    // pass 2: quantize straight into A-fragments (row-major == A-layout)
    ix4 a2f[2];
#pragma unroll
    for (int half = 0; half < 2; ++half) {
      const int base = half * 64 + g * 16;
#pragma unroll
      for (int q = 0; q < 4; ++q) {
        fx4 v  = *reinterpret_cast<const fx4*>(hrow + base + q * 4);
        fx4 s4 = *reinterpret_cast<const fx4*>(sc2 + base + q * 4);
        int c0 = (int)fminf(fmaxf(rintf(v[0] * s4[0] * gq2), -128.f), 127.f);
        int c1 = (int)fminf(fmaxf(rintf(v[1] * s4[1] * gq2), -128.f), 127.f);
        int c2 = (int)fminf(fmaxf(rintf(v[2] * s4[2] * gq2), -128.f), 127.f);
        int c3 = (int)fminf(fmaxf(rintf(v[3] * s4[3] * gq2), -128.f), 127.f);
        a2f[half][q] = (int)((unsigned)(c0 & 255) | ((unsigned)(c1 & 255) << 8) |
                             ((unsigned)(c2 & 255) << 16) | ((unsigned)(c3 & 255) << 24));
      }
    }

    // dequant scales for the tokens this lane's D rows cover
    float i2tok[4];
#pragma unroll
    for (int r = 0; r < 4; ++r) i2tok[r] = __shfl(i2self, 4 * g + r, 64);

    // MFMA2 per nt-block; immediately dequant+relu into h2f (low reg pressure)
    // D layout: lane (g,sl) -> token 4g+r, channel nt*16+sl
#pragma unroll
    for (int nt = 0; nt < 4; ++nt) {
      const int8_t* bp = t2 + (nt * 16 + sl) * 128 + g * 16;
      ix4 c = {0, 0, 0, 0};
      c = MFMA_I8(a2f[0], *reinterpret_cast<const ix4*>(bp), c);
      c = MFMA_I8(a2f[1], *reinterpret_cast<const ix4*>(bp + 64), c);
#pragma unroll
      for (int r = 0; r < 4; ++r)
        h2f[(4 * g + r) * 68 + nt * 16 + sl] =
            fmaxf((float)c[r] * i2tok[r] * m2, 0.f);
    }
    wave_lds_fence();  // same-wave write->read, no barrier needed

    // re-read token-major: lane (g,sl) = token sl, channels 16g..16g+15
    // (this IS MFMA3's A-fragment layout -> no transpose, no k-permutation)
    fx4 hv[4], s4v[4];
#pragma unroll
    for (int q = 0; q < 4; ++q) {
      hv[q]  = *reinterpret_cast<const fx4*>(&h2f[sl * 68 + g * 16 + q * 4]);
      s4v[q] = *reinterpret_cast<const fx4*>(sc3 + g * 16 + q * 4);
    }
    float ss3 = 0.f, am3 = 0.f;
#pragma unroll
    for (int q = 0; q < 4; ++q) {
      fx4 v = hv[q], s4 = s4v[q];
      ss3 += v[0]*v[0] + v[1]*v[1] + v[2]*v[2] + v[3]*v[3];
      am3 = fmaxf(am3, fmaxf(fmaxf(fabsf(v[0]*s4[0]), fabsf(v[1]*s4[1])),
                             fmaxf(fabsf(v[2]*s4[2]), fabsf(v[3]*s4[3]))));
    }
    ss3 += __shfl_xor(ss3, 16, 64);
    am3 = fmaxf(am3, __shfl_xor(am3, 16, 64));
    ss3 += __shfl_xor(ss3, 32, 64);
    am3 = fmaxf(am3, __shfl_xor(am3, 32, 64));
    const float den3 = sqrtf(ss3) * 0.125f + 1e-8f;  // 1/sqrt(64)
    const float id3  = 1.0f / den3;
    const float cl3  = fmaxf(am3 * id3, 1e-5f);
    const float gq3  = (127.0f / cl3) * id3;
    const float i3self = cl3 * (1.0f / 127.0f) * m3;  // token sl out scale

    // quant3 directly into the A-fragment
    ix4 a3;
#pragma unroll
    for (int q = 0; q < 4; ++q) {
      fx4 v = hv[q], s4 = s4v[q];
      int c0 = (int)fminf(fmaxf(rintf(v[0] * s4[0] * gq3), -128.f), 127.f);
      int c1 = (int)fminf(fmaxf(rintf(v[1] * s4[1] * gq3), -128.f), 127.f);
      int c2 = (int)fminf(fmaxf(rintf(v[2] * s4[2] * gq3), -128.f), 127.f);
      int c3 = (int)fminf(fmaxf(rintf(v[3] * s4[3] * gq3), -128.f), 127.f);
      a3[q] = (int)((unsigned)(c0 & 255) | ((unsigned)(c1 & 255) << 8) |
                    ((unsigned)(c2 & 255) << 16) | ((unsigned)(c3 & 255) << 24));
    }

    // MFMA3: M=16 tokens, N=16 (10 used), K=64; B[k=16g+j][n=sl] = t3[sl][16g+j]
    ix4 b3 = *reinterpret_cast<const ix4*>(t3 + sl * 64 + g * 16);
    ix4 acc3 = {0, 0, 0, 0};
    acc3 = MFMA_I8(a3, b3, acc3);

    // D: lane (g,sl) -> token 4g+r, col sl; need out-scale of token 4g+r
    float i3tok[4];
#pragma unroll
    for (int r = 0; r < 4; ++r) i3tok[r] = __shfl(i3self, 4 * g + r, 64);

    if (sl < 10) {
#pragma unroll
      for (int r = 0; r < 4; ++r)
        out[(size_t)(tile * 16 + 4 * g + r) * 10 + sl] = (float)acc3[r] * i3tok[r];
    }
  }
}

// ---------------------------------------------------------------- launch
extern "C" void kernel_launch(void* const* d_in, const int* in_sizes, int n_in,
                              void* d_out, int out_size, void* d_ws, size_t ws_size,
                              hipStream_t stream) {
  const float* x  = (const float*)d_in[0];
  const float* w1 = (const float*)d_in[1];
  const float* s1 = (const float*)d_in[2];
  const float* w2 = (const float*)d_in[3];
  const float* s2 = (const float*)d_in[4];
  const float* w3 = (const float*)d_in[5];
  const float* s3 = (const float*)d_in[6];
  float* out = (float*)d_out;

  char* ws = (char*)d_ws;
  double* part   = (double*)ws;            // 256 doubles (249 used)
  double* finals = (double*)(ws + 2048);   // 3 doubles
  int8_t* t1     = (int8_t*)(ws + 4096);
  int8_t* t2     = (int8_t*)(ws + 110592);
  int8_t* t3     = (int8_t*)(ws + 118784);

  const int B = in_sizes[0] / 784;
  const int numTiles = B / 16;

  prep_mean<<<249, 256, 0, stream>>>(w1, w2, w3, part);
  const int total_q = 128 * 832 + 64 * 128 + 16 * 64;  // 115712
  prep_quant<<<(total_q + 255) / 256, 256, 0, stream>>>(w1, w2, w3, part, finals,
                                                        t1, t2, t3);
  ffn_fused<<<numTiles, 256, 0, stream>>>(x, s1, s2, s3, t1, t2, t3, finals, out);
}